// Round 8
// baseline (45.382 us; speedup 1.0000x reference)
//
#include <hip/hip_runtime.h>

// G=16, H=8, N=128/side, HD=32, D=256
// x tensors are plain row-major [2048][256]; head (g,h) chunk = rows g*128+h*16..+16
// viewed flat as [128 nodes][32].
#define C2L2E 2.8853900817779268f   // 2*log2(e)
#define LOG2E 1.4426950408889634f

// ws float offsets
#define WS_X1   0          // [2048][256] f32 x1
#define WS_X2   524288     // [2048][256] f32 x2
#define WS_RS   1048576    // [gh][128] row sums
#define WS_CP   1064960    // [gh][2][128] col partials
// bf16 hi/lo staging (ushort counts; float offset = /2)
#define WS_AH   1114112    // A hi  [2048][256] bf16
#define WS_AL   1376256
#define WS_BH   1638400
#define WS_BL   1900544
#define WS_W1H  2162688    // W1 hi [256][256]
#define WS_W1L  2195456
#define WS_W2H  2228224
#define WS_W2L  2260992

// K2 LDS float offsets
#define L_SMAT 0
#define L_COLP 8448
#define L_RED8 8960
#define L_X2   9216
#define L_X1   13312

typedef short bf16x8 __attribute__((ext_vector_type(8)));
typedef float f32x4 __attribute__((ext_vector_type(4)));

__device__ __forceinline__ int swz4(int row, int c4) { return (c4 ^ (row & 7)) << 2; }

__device__ __forceinline__ unsigned short bf16rne(float f) {
    unsigned u = __float_as_uint(f);
    u += 0x7FFF + ((u >> 16) & 1);
    return (unsigned short)(u >> 16);
}
__device__ __forceinline__ float bf16tof(unsigned short h) {
    return __uint_as_float(((unsigned)h) << 16);
}

// ================= K0: fp32 -> bf16 hi/lo split =================
// grid 576 x 512: float4 idx: A[0,131072) B[131072,262144) W1[262144,278528) W2[278528,294912)
__global__ __launch_bounds__(512) void k0_convert(
        const float* __restrict__ A, const float* __restrict__ B,
        const float* __restrict__ W1, const float* __restrict__ W2,
        float* __restrict__ ws) {
    const int idx = blockIdx.x * 512 + threadIdx.x;
    const float* src; unsigned short *dh, *dl; int base;
    if (idx < 131072)      { src = A;  dh = (unsigned short*)(ws + WS_AH);  dl = (unsigned short*)(ws + WS_AL);  base = idx; }
    else if (idx < 262144) { src = B;  dh = (unsigned short*)(ws + WS_BH);  dl = (unsigned short*)(ws + WS_BL);  base = idx - 131072; }
    else if (idx < 278528) { src = W1; dh = (unsigned short*)(ws + WS_W1H); dl = (unsigned short*)(ws + WS_W1L); base = idx - 262144; }
    else                   { src = W2; dh = (unsigned short*)(ws + WS_W2H); dl = (unsigned short*)(ws + WS_W2L); base = idx - 278528; }
    float4 v = ((const float4*)src)[base];
    ushort4 h, l;
    h.x = bf16rne(v.x); l.x = bf16rne(v.x - bf16tof(h.x));
    h.y = bf16rne(v.y); l.y = bf16rne(v.y - bf16tof(h.y));
    h.z = bf16rne(v.z); l.z = bf16rne(v.z - bf16tof(h.z));
    h.w = bf16rne(v.w); l.w = bf16rne(v.w - bf16tof(h.w));
    ((ushort4*)dh)[base] = h;
    ((ushort4*)dl)[base] = l;
}

// ================= K1: split-bf16 MFMA GEMM x = In @ W^T + bias =================
// grid 256: mat=bid>>7; idx=bid&127 -> r0=(idx>>2)*64, c0=(idx&3)*64. 256 thr = 4 waves.
// Wave wv: rows r0+wv*16..+16. Frags: A row=lane&15,k=(lane>>4)*8+j; B col=lane&15 same k.
__global__ __launch_bounds__(256) void k1_mfma(
        const float* __restrict__ b1, const float* __restrict__ b2,
        float* __restrict__ ws) {
    const int bid = blockIdx.x, tid = threadIdx.x;
    const int mat = bid >> 7, idx = bid & 127;
    const int r0 = (idx >> 2) * 64, c0 = (idx & 3) * 64;
    const unsigned short* IH = (const unsigned short*)(ws + (mat ? WS_BH : WS_AH));
    const unsigned short* IL = (const unsigned short*)(ws + (mat ? WS_BL : WS_AL));
    const unsigned short* WH = (const unsigned short*)(ws + (mat ? WS_W2H : WS_W1H));
    const unsigned short* WL = (const unsigned short*)(ws + (mat ? WS_W2L : WS_W1L));
    const float* bs = mat ? b2 : b1;
    float* xo = ws + (mat ? WS_X2 : WS_X1);

    const int wv = tid >> 6, lane = tid & 63;
    const int l16 = lane & 15, khi = (lane >> 4) * 8;
    const int row = r0 + wv * 16 + l16;

    f32x4 acc[4];
    #pragma unroll
    for (int nt = 0; nt < 4; ++nt) acc[nt] = (f32x4){0.f, 0.f, 0.f, 0.f};

    const unsigned short* ihp = IH + (size_t)row * 256 + khi;
    const unsigned short* ilp = IL + (size_t)row * 256 + khi;

    for (int kt = 0; kt < 8; ++kt) {
        bf16x8 ah = *(const bf16x8*)(ihp + kt * 32);
        bf16x8 al = *(const bf16x8*)(ilp + kt * 32);
        #pragma unroll
        for (int nt = 0; nt < 4; ++nt) {
            const int cB = c0 + nt * 16 + l16;
            bf16x8 wh = *(const bf16x8*)(WH + (size_t)cB * 256 + kt * 32 + khi);
            bf16x8 wl = *(const bf16x8*)(WL + (size_t)cB * 256 + kt * 32 + khi);
            acc[nt] = __builtin_amdgcn_mfma_f32_16x16x32_bf16(ah, wh, acc[nt], 0, 0, 0);
            acc[nt] = __builtin_amdgcn_mfma_f32_16x16x32_bf16(ah, wl, acc[nt], 0, 0, 0);
            acc[nt] = __builtin_amdgcn_mfma_f32_16x16x32_bf16(al, wh, acc[nt], 0, 0, 0);
        }
    }

    const int rowb = r0 + wv * 16 + (lane >> 4) * 4;   // C/D: row=(lane>>4)*4+reg, col=lane&15
    #pragma unroll
    for (int nt = 0; nt < 4; ++nt) {
        const int col = c0 + nt * 16 + l16;
        const float bb = bs[col];
        #pragma unroll
        for (int rg = 0; rg < 4; ++rg)
            xo[(size_t)(rowb + rg) * 256 + col] = acc[nt][rg] + bb;
    }
}

// ================= K2: tanh-att partials (verified) =================
__global__ __launch_bounds__(512) void k2_att(
        float* __restrict__ ws, const float* __restrict__ q) {
    __shared__ float sm[15360];
    const int tid = threadIdx.x;
    const int gh = blockIdx.x >> 1, s = blockIdx.x & 1;
    float* x2L = sm + L_X2;
    float* x1L = sm + L_X1;

    {
        const float4* src2 = (const float4*)(ws + WS_X2 + (size_t)gh * 4096);
        #pragma unroll
        for (int p = 0; p < 2; ++p) {
            int n = tid + p * 512;
            float4 v = src2[n];
            int ni = n >> 3, c4 = n & 7;
            *(float4*)(x2L + ni * 32 + swz4(ni, c4)) = v;
        }
        const float4* src1 = (const float4*)(ws + WS_X1 + (size_t)gh * 4096 + s * 2048);
        float4 v = src1[tid];
        int nl = tid >> 3, c4 = tid & 7;
        *(float4*)(x1L + nl * 32 + swz4(nl, c4)) = v;
    }
    __syncthreads();

    {
        const int j = tid & 127, iset = tid >> 7;
        float xr[32], qt[32];
        #pragma unroll
        for (int cc = 0; cc < 8; ++cc) {
            float4 v = *(float4*)(x2L + j * 32 + swz4(j, cc));
            xr[cc*4+0] = v.x * C2L2E; xr[cc*4+1] = v.y * C2L2E;
            xr[cc*4+2] = v.z * C2L2E; xr[cc*4+3] = v.w * C2L2E;
            float4 qv = *(const float4*)(q + cc * 4);
            qt[cc*4+0] = -2.f * qv.x; qt[cc*4+1] = -2.f * qv.y;
            qt[cc*4+2] = -2.f * qv.z; qt[cc*4+3] = -2.f * qv.w;
        }
        float colacc = 0.f;
        for (int rr = 0; rr < 16; ++rr) {
            const int r = iset * 16 + rr;
            float a[32];
            #pragma unroll
            for (int cc = 0; cc < 8; ++cc) {
                float4 v = *(float4*)(x1L + r * 32 + swz4(r, cc));
                a[cc*4+0] = v.x; a[cc*4+1] = v.y; a[cc*4+2] = v.z; a[cc*4+3] = v.w;
            }
            float S0 = 0.f, S1 = 0.f;
            #pragma unroll
            for (int kp = 0; kp < 16; ++kp) {
                float p0 = a[2*kp]   * xr[2*kp];
                float p1 = a[2*kp+1] * xr[2*kp+1];
                float d0 = __builtin_amdgcn_exp2f(fminf(p0, 60.f)) + 1.f;
                float d1 = __builtin_amdgcn_exp2f(fminf(p1, 60.f)) + 1.f;
                float rD = __builtin_amdgcn_rcpf(d0 * d1);
                float U  = fmaf(qt[2*kp+1], d0, qt[2*kp] * d1);
                if (kp & 1) S1 = fmaf(U, rD, S1); else S0 = fmaf(U, rD, S0);
            }
            float S = S0 + S1;
            colacc += S;
            sm[L_SMAT + r * 132 + j] = S;
        }
        sm[L_COLP + iset * 128 + j] = colacc;
    }
    __syncthreads();

    if (tid < 256) {
        const int row = tid >> 2, seg = tid & 3;
        float acc = 0.f;
        #pragma unroll
        for (int m = 0; m < 8; ++m) {
            float4 v = *(float4*)(sm + L_SMAT + row * 132 + seg * 32 + m * 4);
            acc += (v.x + v.y) + (v.z + v.w);
        }
        sm[L_RED8 + row * 4 + seg] = acc;
    }
    __syncthreads();
    if (tid < 64) {
        float v = sm[L_RED8 + tid*4] + sm[L_RED8 + tid*4+1]
                + sm[L_RED8 + tid*4+2] + sm[L_RED8 + tid*4+3];
        ws[WS_RS + gh * 128 + s * 64 + tid] = v;
    } else if (tid < 192) {
        const int j = tid - 64;
        ws[WS_CP + (size_t)(gh * 2 + s) * 128 + j] =
            sm[L_COLP + j] + sm[L_COLP + 128 + j] + sm[L_COLP + 256 + j] + sm[L_COLP + 384 + j];
    }
}

// ================= K3: softmaxes + weighted sums -> out (verified) =================
__global__ __launch_bounds__(256) void kb_finish(
        const float* __restrict__ ws, float* __restrict__ out) {
    const int gh = blockIdx.x;
    const int g = gh >> 3, h = gh & 7;
    const int tid = threadIdx.x;
    const int side = tid >> 7;
    const int u = tid & 127;
    const int w2 = (u >> 6) & 1;
    const int lane = tid & 63;

    __shared__ float warr[2][128];
    __shared__ float red[4];
    __shared__ float red2[4];
    __shared__ float part[2][4][32];

    float m;
    if (side == 0) {
        m = ws[WS_RS + gh * 128 + u] * 0.0078125f;
    } else {
        m = (ws[WS_CP + (size_t)(gh * 2 + 0) * 128 + u] +
             ws[WS_CP + (size_t)(gh * 2 + 1) * 128 + u]) * 0.0078125f;
    }

    float mx = m;
    #pragma unroll
    for (int d = 32; d >= 1; d >>= 1) mx = fmaxf(mx, __shfl_xor(mx, d));
    if (lane == 0) red[side * 2 + w2] = mx;
    __syncthreads();
    mx = fmaxf(red[side * 2], red[side * 2 + 1]);

    float e = __builtin_amdgcn_exp2f((m - mx) * LOG2E);
    float sme = e;
    #pragma unroll
    for (int d = 32; d >= 1; d >>= 1) sme += __shfl_xor(sme, d);
    if (lane == 0) red2[side * 2 + w2] = sme;
    __syncthreads();
    const float tot = red2[side * 2] + red2[side * 2 + 1];
    warr[side][u] = e * __builtin_amdgcn_rcpf(tot);
    __syncthreads();

    const int k = u & 31, is = u >> 5;
    const float* xt = ws + (side ? WS_X2 : WS_X1) + (size_t)gh * 4096;
    float p = 0.f;
    #pragma unroll 4
    for (int r = 0; r < 32; ++r)
        p = fmaf(xt[(is * 32 + r) * 32 + k], warr[side][is * 32 + r], p);
    part[side][is][k] = p;
    __syncthreads();
    if (u < 32 && side == 0) {
        float o = part[0][0][u] + part[0][1][u] + part[0][2][u] + part[0][3][u];
        out[(size_t)g * 512 + h * 32 + u] = o;
    } else if (u < 32 && side == 1) {
        float o = part[1][0][u] + part[1][1][u] + part[1][2][u] + part[1][3][u];
        out[(size_t)g * 512 + 256 + h * 32 + u] = o;
    }
}

extern "C" void kernel_launch(void* const* d_in, const int* in_sizes, int n_in,
                              void* d_out, int out_size, void* d_ws, size_t ws_size,
                              hipStream_t stream) {
    const float* A  = (const float*)d_in[0];
    const float* B  = (const float*)d_in[2];
    const float* W1 = (const float*)d_in[4];
    const float* b1 = (const float*)d_in[5];
    const float* W2 = (const float*)d_in[6];
    const float* b2 = (const float*)d_in[7];
    const float* q  = (const float*)d_in[8];
    float* ws  = (float*)d_ws;
    float* out = (float*)d_out;

    k0_convert<<<576, 512, 0, stream>>>(A, B, W1, W2, ws);
    k1_mfma<<<256, 256, 0, stream>>>(b1, b2, ws);
    k2_att<<<256, 512, 0, stream>>>(ws, q);
    kb_finish<<<128, 256, 0, stream>>>(ws, out);
}